// Round 5
// baseline (197.004 us; speedup 1.0000x reference)
//
#include <hip/hip_runtime.h>

// Problem constants (from reference)
static constexpr int kB = 2, kS = 2048, kD = 1024, kFF = 4096;
static constexpr int kM = kB * kS;  // 4096 token rows
static constexpr size_t MB = 1u << 20;

typedef __attribute__((ext_vector_type(8))) short short8;
typedef __attribute__((ext_vector_type(4))) float f32x4;

__device__ __forceinline__ unsigned short f2bf(float f) {
  union { float f; unsigned int u; } c; c.f = f;
  unsigned int u = c.u;
  unsigned int r = u + 0x7FFFu + ((u >> 16) & 1u);  // RNE
  return (unsigned short)(r >> 16);
}

__device__ __forceinline__ float bf2f(unsigned short b) {
  union { unsigned int u; float f; } c;
  c.u = ((unsigned int)b) << 16;
  return c.f;
}

__device__ __forceinline__ void gload_lds16(const void* g, void* l) {
  __builtin_amdgcn_global_load_lds(
      (const __attribute__((address_space(1))) void*)g,
      (__attribute__((address_space(3))) void*)l, 16, 0, 0);
}

// ---------------- cast fp32 -> bf16 (vectorized) ----------------
__global__ __launch_bounds__(256) void cast_bf16_kernel(
    const float* __restrict__ in, unsigned short* __restrict__ out, int n) {
  int i = (blockIdx.x * 256 + threadIdx.x) * 4;
  if (i >= n) return;
  float4 v = *(const float4*)(in + i);
  ushort4 o;
  o.x = f2bf(v.x); o.y = f2bf(v.y); o.z = f2bf(v.z); o.w = f2bf(v.w);
  *(ushort4*)(out + i) = o;
}

// ------------- cast + transpose: W[K][N] fp32 -> Wt[N][K] bf16 (× scale) -------------
__global__ __launch_bounds__(1024) void cast_transpose_kernel(
    const float* __restrict__ W, unsigned short* __restrict__ Wt,
    int K, int N, float scale) {
  __shared__ float tile[32][33];
  int nb = blockIdx.x * 32, kb = blockIdx.y * 32;
  int tx = threadIdx.x, ty = threadIdx.y;
  tile[ty][tx] = W[(size_t)(kb + ty) * N + (nb + tx)];
  __syncthreads();
  Wt[(size_t)(nb + ty) * K + (kb + tx)] = f2bf(tile[tx][ty] * scale);
}

// --------- parallel GEMV phase 1: partial[b][n] = sum_{f in block b} bv[f]*Wo[f][n] ---
__global__ __launch_bounds__(256) void bias_gemv_part_kernel(
    const float* __restrict__ bv, const float* __restrict__ Wo,
    float* __restrict__ partial) {
  const int b = blockIdx.x, t = threadIdx.x;
  const int c = t * 4;
  float4 acc = {0.f, 0.f, 0.f, 0.f};
#pragma unroll
  for (int r = 0; r < 8; ++r) {
    const int f = b * 8 + r;
    const float s = bv[f];
    float4 w = *(const float4*)(Wo + (size_t)f * 1024 + c);
    acc.x = fmaf(s, w.x, acc.x);
    acc.y = fmaf(s, w.y, acc.y);
    acc.z = fmaf(s, w.z, acc.z);
    acc.w = fmaf(s, w.w, acc.w);
  }
  *(float4*)(partial + (size_t)b * 1024 + c) = acc;
}

// --------- GEMV phase 2: bc[n] = 2048 * sum_b partial[b][n] + bo[n] ---------
__global__ __launch_bounds__(256) void bias_gemv_fin_kernel(
    const float* __restrict__ partial, const float* __restrict__ bo,
    float* __restrict__ bc) {
  const int n = blockIdx.x * 256 + threadIdx.x;
  float acc = 0.0f;
#pragma unroll 8
  for (int b = 0; b < 128; ++b) acc += partial[(size_t)b * 1024 + n];
  bc[n] = 2048.0f * acc + bo[n];
}

// -------- combine 4 fp32 split-K partials of Wc, add identity, cast bf16 --------
__global__ __launch_bounds__(256) void combine_wc_kernel(
    const float* __restrict__ P, unsigned short* __restrict__ Wt) {
  const int i = (blockIdx.x * 256 + threadIdx.x) * 4;  // grid 1024
  const int MN = 1024 * 1024;
  float4 s0 = *(const float4*)(P + i);
  float4 s1 = *(const float4*)(P + MN + i);
  float4 s2 = *(const float4*)(P + 2 * MN + i);
  float4 s3 = *(const float4*)(P + 3 * MN + i);
  const int row = i >> 10, col = i & 1023;
  float v0 = s0.x + s1.x + s2.x + s3.x + (row == col + 0 ? 1.0f : 0.0f);
  float v1 = s0.y + s1.y + s2.y + s3.y + (row == col + 1 ? 1.0f : 0.0f);
  float v2 = s0.z + s1.z + s2.z + s3.z + (row == col + 2 ? 1.0f : 0.0f);
  float v3 = s0.w + s1.w + s2.w + s3.w + (row == col + 3 ? 1.0f : 0.0f);
  ushort4 o; o.x = f2bf(v0); o.y = f2bf(v1); o.z = f2bf(v2); o.w = f2bf(v3);
  *(ushort4*)(Wt + i) = o;
}

// ---------------- 128x128 2-phase GEMM (kept for the small Wc product) ----------------
template <int OUT_BF16, int RELU>
__global__ __launch_bounds__(256) void gemm_bt(
    const unsigned short* __restrict__ A, const unsigned short* __restrict__ Bt,
    const float* __restrict__ bias, void* __restrict__ Cout,
    int M, int N, int K, int nXtiles, int nTilesPerSplit, int kSplitLen,
    size_t cSplitStride) {
  __shared__ __align__(16) unsigned short sA[128 * 64];
  __shared__ __align__(16) unsigned short sB[128 * 64];
  const int tid = threadIdx.x;
  const int wave = tid >> 6, lane = tid & 63;
  const int wr = wave >> 1, wc = wave & 1;
  const int nwg = gridDim.x;
  const int q = nwg >> 3, r = nwg & 7;
  const int xcd = blockIdx.x & 7, pos = blockIdx.x >> 3;
  const int swz = (xcd < r) ? (xcd * (q + 1) + pos) : (r * (q + 1) + (xcd - r) * q + pos);
  const int split = swz / nTilesPerSplit, rem = swz % nTilesPerSplit;
  const int m0 = (rem / nXtiles) * 128, n0 = (rem % nXtiles) * 128;
  const int kBeg = split * kSplitLen, kEnd = kBeg + kSplitLen;
  const int srow = lane >> 3;
  const int scol = ((lane & 7) ^ srow) * 8;

  f32x4 acc[4][4] = {};

  for (int k0 = kBeg; k0 < kEnd; k0 += 64) {
#pragma unroll
    for (int i = 0; i < 4; ++i) {
      const int chunk = i * 4 + wave;
      const int rr = chunk * 8 + srow;
      gload_lds16(A + (size_t)(m0 + rr) * K + (k0 + scol), &sA[chunk * 512]);
      gload_lds16(Bt + (size_t)(n0 + rr) * K + (k0 + scol), &sB[chunk * 512]);
    }
    __syncthreads();
#pragma unroll
    for (int kk = 0; kk < 64; kk += 32) {
      const int kcol = kk + (lane >> 4) * 8;
      const int kswz = (lane & 7) * 8;
      short8 af[4], bfr[4];
#pragma unroll
      for (int m = 0; m < 4; ++m)
        af[m] = *(const short8*)&sA[(wr * 64 + m * 16 + (lane & 15)) * 64 + (kcol ^ kswz)];
#pragma unroll
      for (int n = 0; n < 4; ++n)
        bfr[n] = *(const short8*)&sB[(wc * 64 + n * 16 + (lane & 15)) * 64 + (kcol ^ kswz)];
#pragma unroll
      for (int m = 0; m < 4; ++m)
#pragma unroll
        for (int n = 0; n < 4; ++n)
          acc[m][n] = __builtin_amdgcn_mfma_f32_16x16x32_bf16(af[m], bfr[n], acc[m][n], 0, 0, 0);
    }
    __syncthreads();
  }

  const int cl = lane & 15, rg = lane >> 4;
  const float* bptr = (split == 0) ? bias : nullptr;
#pragma unroll
  for (int n = 0; n < 4; ++n) {
    const int col = n0 + wc * 64 + n * 16 + cl;
    const float bias_v = bptr ? bptr[col] : 0.0f;
#pragma unroll
    for (int m = 0; m < 4; ++m) {
      const int rbase = m0 + wr * 64 + m * 16 + rg * 4;
#pragma unroll
      for (int j = 0; j < 4; ++j) {
        float v = acc[m][n][j] + bias_v;
        if (RELU) v = fmaxf(v, 0.0f);
        if (OUT_BF16)
          ((unsigned short*)Cout)[(size_t)(rbase + j) * N + col] = f2bf(v);
        else
          ((float*)Cout)[split * cSplitStride + (size_t)(rbase + j) * N + col] = v;
      }
    }
  }
}

// ================= 256x256 8-phase GEMM (T3+T4+T2+T5+T1) =================
// 8 waves (2M x 4N), BK=64, 4 x 32KB LDS buffers (A/B x double-buffer).
// Per K-tile: 4 phases {12 ds_read || stage 2 gload_lds(next tile) -> barrier
// -> setprio(1) -> 16 MFMA -> setprio(0) -> barrier}; ONE vmcnt(0) per K-tile
// at phase 4 (next-tile loads in flight across ~3 phases). Race-free: tile t+1
// staged into the buffer whose reads finished at the barrier ending tile t-1.

#define STAGE2(SAW, SBW, G, KOFS)                                              \
  gload_lds16(aSrc + (size_t)(G) * 64 * K + (KOFS), &SAW[(G) * 4096 + wid * 512]); \
  gload_lds16(bSrc + (size_t)(G) * 64 * K + (KOFS), &SBW[(G) * 4096 + wid * 512]);

#define KTILE(SAR, SBR, SAW, SBW, MORE, KNEXT)                                 \
  {                                                                            \
    _Pragma("unroll")                                                          \
    for (int p = 0; p < 4; ++p) {                                              \
      const int mh = p >> 1, nh = p & 1;                                       \
      short8 av[4][2], bw[2][2];                                               \
      _Pragma("unroll")                                                        \
      for (int fm = 0; fm < 4; ++fm) {                                         \
        const int ra = (rA + mh * 64 + fm * 16) * 64;                          \
        av[fm][0] = *(const short8*)&SAR[ra + cK0];                            \
        av[fm][1] = *(const short8*)&SAR[ra + cK1];                            \
      }                                                                        \
      _Pragma("unroll")                                                        \
      for (int fn = 0; fn < 2; ++fn) {                                         \
        const int rb = (rB + nh * 32 + fn * 16) * 64;                          \
        bw[fn][0] = *(const short8*)&SBR[rb + cK0];                            \
        bw[fn][1] = *(const short8*)&SBR[rb + cK1];                            \
      }                                                                        \
      if (MORE) { STAGE2(SAW, SBW, p, KNEXT) }                                 \
      asm volatile("s_barrier" ::: "memory");                                  \
      __builtin_amdgcn_s_setprio(1);                                           \
      _Pragma("unroll")                                                        \
      for (int fm = 0; fm < 4; ++fm) {                                         \
        _Pragma("unroll")                                                      \
        for (int fn = 0; fn < 2; ++fn) {                                       \
          acc[mh * 4 + fm][nh * 2 + fn] = __builtin_amdgcn_mfma_f32_16x16x32_bf16( \
              av[fm][0], bw[fn][0], acc[mh * 4 + fm][nh * 2 + fn], 0, 0, 0);   \
          acc[mh * 4 + fm][nh * 2 + fn] = __builtin_amdgcn_mfma_f32_16x16x32_bf16( \
              av[fm][1], bw[fn][1], acc[mh * 4 + fm][nh * 2 + fn], 0, 0, 0);   \
        }                                                                      \
      }                                                                        \
      __builtin_amdgcn_s_setprio(0);                                           \
      if (p == 3 && (MORE)) asm volatile("s_waitcnt vmcnt(0)" ::: "memory");   \
      asm volatile("s_barrier" ::: "memory");                                  \
    }                                                                          \
  }

template <int OUT_BF16, int RELU>
__global__ __launch_bounds__(512, 2) void gemm256(
    const unsigned short* __restrict__ A, const unsigned short* __restrict__ Bt,
    const float* __restrict__ bias, void* __restrict__ Cout,
    int M, int N, int K, int nXtiles, int nTilesPerSplit, int kSplitLen,
    size_t cStride) {
  __shared__ __align__(16) unsigned short sA0[256 * 64];
  __shared__ __align__(16) unsigned short sA1[256 * 64];
  __shared__ __align__(16) unsigned short sB0[256 * 64];
  __shared__ __align__(16) unsigned short sB1[256 * 64];

  const int tid = threadIdx.x;
  const int wid = tid >> 6, lane = tid & 63;
  const int wr = wid >> 2, wq = wid & 3;
  const int l15 = lane & 15, l7 = lane & 7, l4 = lane >> 4;

  // T1: bijective XCD swizzle
  const int nwg = gridDim.x;
  const int q = nwg >> 3, r = nwg & 7;
  const int xcd = blockIdx.x & 7, pos = blockIdx.x >> 3;
  const int swz = (xcd < r) ? (xcd * (q + 1) + pos) : (r * (q + 1) + (xcd - r) * q + pos);
  const int split = swz / nTilesPerSplit, rem = swz % nTilesPerSplit;
  const int m0 = (rem / nXtiles) * 256, n0 = (rem % nXtiles) * 256;
  const int kBeg = split * kSplitLen;
  const int nt = kSplitLen >> 6;  // K-tiles (always even here: 4 or 16)

  // staging: wave wid stages rows [g*64 + wid*8, +8); lane -> row (lane>>3),
  // pre-swizzled source col slot (l7 ^ (lane>>3)); LDS dest stays linear.
  const int srow = lane >> 3;
  const int sColOff = ((l7 ^ srow) << 3);
  const unsigned short* aSrc = A + (size_t)(m0 + wid * 8 + srow) * K + kBeg + sColOff;
  const unsigned short* bSrc = Bt + (size_t)(n0 + wid * 8 + srow) * K + kBeg + sColOff;

  // read-side swizzled K offsets (elements): slot = (kh*4 + l4) ^ l7
  const int cK0 = ((l4 ^ l7) << 3);
  const int cK1 = (((4 + l4) ^ l7) << 3);
  const int rA = wr * 128 + l15;
  const int rB = wq * 64 + l15;

  f32x4 acc[8][4] = {};

  // prologue: stage tile 0 fully into buffer 0
  STAGE2(sA0, sB0, 0, 0)
  STAGE2(sA0, sB0, 1, 0)
  STAGE2(sA0, sB0, 2, 0)
  STAGE2(sA0, sB0, 3, 0)
  __syncthreads();  // drains vmcnt(0)

  for (int t = 0; t < nt; t += 2) {
    KTILE(sA0, sB0, sA1, sB1, true, (t + 1) * 64)
    const bool more1 = (t + 2) < nt;
    KTILE(sA1, sB1, sA0, sB0, more1, (t + 2) * 64)
  }

  // epilogue: C-write. frag f covers rows +f*16, frag n covers cols +n*16.
  const int colBase = n0 + wq * 64;
  const int rowBase = m0 + wr * 128 + l4 * 4;
  const float* bptr = (split == 0) ? bias : nullptr;
#pragma unroll
  for (int fn = 0; fn < 4; ++fn) {
    const int col = colBase + fn * 16 + l15;
    const float bias_v = bptr ? bptr[col] : 0.0f;
#pragma unroll
    for (int fm = 0; fm < 8; ++fm) {
      const int row = rowBase + fm * 16;
#pragma unroll
      for (int j = 0; j < 4; ++j) {
        float v = acc[fm][fn][j] + bias_v;
        if (RELU) v = fmaxf(v, 0.0f);
        if (OUT_BF16)
          ((unsigned short*)Cout)[(size_t)(row + j) * N + col] = f2bf(v);
        else
          ((float*)Cout)[split * cStride + (size_t)(row + j) * N + col] = v;
      }
    }
  }
}

// -------- LN over D=1024 of sum of 4 fp32 partials -> bf16 out --------
__global__ __launch_bounds__(256) void ln4_bf16_kernel(
    const float* __restrict__ P, size_t pStr,
    const float* __restrict__ gg, const float* __restrict__ bb,
    unsigned short* __restrict__ Hb) {
  const int row = blockIdx.x, t = threadIdx.x;
  const size_t base = (size_t)row * 1024 + t * 4;
  float4 v0 = *(const float4*)(P + base);
  float4 v1 = *(const float4*)(P + pStr + base);
  float4 v2 = *(const float4*)(P + 2 * pStr + base);
  float4 v3 = *(const float4*)(P + 3 * pStr + base);
  float a0 = v0.x + v1.x + v2.x + v3.x;
  float a1 = v0.y + v1.y + v2.y + v3.y;
  float a2 = v0.z + v1.z + v2.z + v3.z;
  float a3 = v0.w + v1.w + v2.w + v3.w;
  float s = a0 + a1 + a2 + a3;
  float ss = a0 * a0 + a1 * a1 + a2 * a2 + a3 * a3;
#pragma unroll
  for (int off = 32; off > 0; off >>= 1) {
    s += __shfl_down(s, off);
    ss += __shfl_down(ss, off);
  }
  __shared__ float rs[4], rss[4];
  __shared__ float smean, srstd;
  const int wave = t >> 6, lane = t & 63;
  if (lane == 0) { rs[wave] = s; rss[wave] = ss; }
  __syncthreads();
  if (t == 0) {
    float S1 = rs[0] + rs[1] + rs[2] + rs[3];
    float S2 = rss[0] + rss[1] + rss[2] + rss[3];
    float mean = S1 * (1.0f / 1024.0f);
    float var = S2 * (1.0f / 1024.0f) - mean * mean;
    smean = mean;
    srstd = rsqrtf(var + 1e-5f);
  }
  __syncthreads();
  const float mean = smean, rstd = srstd;
  float4 gv = *(const float4*)(gg + t * 4);
  float4 bv = *(const float4*)(bb + t * 4);
  ushort4 hb;
  hb.x = f2bf((a0 - mean) * rstd * gv.x + bv.x);
  hb.y = f2bf((a1 - mean) * rstd * gv.y + bv.y);
  hb.z = f2bf((a2 - mean) * rstd * gv.z + bv.z);
  hb.w = f2bf((a3 - mean) * rstd * gv.w + bv.w);
  *(ushort4*)(Hb + base) = hb;
}

// -------- LN of (bf16 residual + sum of 4 fp32 partials) -> fp32 out --------
__global__ __launch_bounds__(256) void ln_fin_kernel(
    const unsigned short* __restrict__ Res, const float* __restrict__ P, size_t pStr,
    const float* __restrict__ gg, const float* __restrict__ bb,
    float* __restrict__ out) {
  const int row = blockIdx.x, t = threadIdx.x;
  const size_t base = (size_t)row * 1024 + t * 4;
  ushort4 rv = *(const ushort4*)(Res + base);
  float4 v0 = *(const float4*)(P + base);
  float4 v1 = *(const float4*)(P + pStr + base);
  float4 v2 = *(const float4*)(P + 2 * pStr + base);
  float4 v3 = *(const float4*)(P + 3 * pStr + base);
  float a0 = bf2f(rv.x) + v0.x + v1.x + v2.x + v3.x;
  float a1 = bf2f(rv.y) + v0.y + v1.y + v2.y + v3.y;
  float a2 = bf2f(rv.z) + v0.z + v1.z + v2.z + v3.z;
  float a3 = bf2f(rv.w) + v0.w + v1.w + v2.w + v3.w;
  float s = a0 + a1 + a2 + a3;
  float ss = a0 * a0 + a1 * a1 + a2 * a2 + a3 * a3;
#pragma unroll
  for (int off = 32; off > 0; off >>= 1) {
    s += __shfl_down(s, off);
    ss += __shfl_down(ss, off);
  }
  __shared__ float rs[4], rss[4];
  __shared__ float smean, srstd;
  const int wave = t >> 6, lane = t & 63;
  if (lane == 0) { rs[wave] = s; rss[wave] = ss; }
  __syncthreads();
  if (t == 0) {
    float S1 = rs[0] + rs[1] + rs[2] + rs[3];
    float S2 = rss[0] + rss[1] + rss[2] + rss[3];
    float mean = S1 * (1.0f / 1024.0f);
    float var = S2 * (1.0f / 1024.0f) - mean * mean;
    smean = mean;
    srstd = rsqrtf(var + 1e-5f);
  }
  __syncthreads();
  const float mean = smean, rstd = srstd;
  float4 gv = *(const float4*)(gg + t * 4);
  float4 bv = *(const float4*)(bb + t * 4);
  float4 ov;
  ov.x = (a0 - mean) * rstd * gv.x + bv.x;
  ov.y = (a1 - mean) * rstd * gv.y + bv.y;
  ov.z = (a2 - mean) * rstd * gv.z + bv.z;
  ov.w = (a3 - mean) * rstd * gv.w + bv.w;
  *(float4*)(out + base) = ov;
}

// ---------------------------------------------------------------------------
// Attention is algebraically dead: softmax over q sums to 1 per (b,h,k) column;
// summed over k -> s_bh == S == 2048 exactly. Folding the residual too:
//   h1  = LN( z @ (I + 2048*Wv@Wo) + (2048*bv@Wo + bo) )
//   out = LN( h1 + relu(h1@W1+b1)@W2 + b2 )
// ---------------------------------------------------------------------------
extern "C" void kernel_launch(void* const* d_in, const int* in_sizes, int n_in,
                              void* d_out, int out_size, void* d_ws, size_t ws_size,
                              hipStream_t stream) {
  const float* z  = (const float*)d_in[2];
  const float* Wv = (const float*)d_in[8];
  const float* bv = (const float*)d_in[9];
  const float* Wo = (const float*)d_in[10];
  const float* bo = (const float*)d_in[11];
  const float* W1 = (const float*)d_in[12];
  const float* b1 = (const float*)d_in[13];
  const float* W2 = (const float*)d_in[14];
  const float* b2 = (const float*)d_in[15];
  const float* lng = (const float*)d_in[16];
  const float* lnb = (const float*)d_in[17];
  float* out = (float*)d_out;

  char* ws = (char*)d_ws;
  // layout (MB offsets), peak exactly 112MB:
  //   attP @0-64   (4 fp32 att partials; dead after LN1) / ffP @0-64 later
  //   zbf  @64-72  (dead after att)  / a1 @64-96 later (overwrites dead wgts too)
  //   WoT @72-74, WvBf @74-76, WcT @76-78, bc @78, bprt @78+0.5
  //   wcp @80-96   (4x4MB fp32 Wc partials; dead after combine)
  //   wT  @96-104  (W1T then W2T)
  //   h1bf @104-112 (alive until LN2)
  float*          attP = (float*)(ws + 0 * MB);
  float*          ffP  = (float*)(ws + 0 * MB);
  unsigned short* zbf  = (unsigned short*)(ws + 64 * MB);
  unsigned short* a1   = (unsigned short*)(ws + 64 * MB);
  unsigned short* WoT  = (unsigned short*)(ws + 72 * MB);
  unsigned short* WvBf = (unsigned short*)(ws + 74 * MB);
  unsigned short* WcT  = (unsigned short*)(ws + 76 * MB);
  float*          bc   = (float*)(ws + 78 * MB);
  float*          bprt = (float*)(ws + 78 * MB + 65536);
  float*          wcp  = (float*)(ws + 80 * MB);
  unsigned short* wT   = (unsigned short*)(ws + 96 * MB);
  unsigned short* h1bf = (unsigned short*)(ws + 104 * MB);

  const int nZ = kM * kD;  // 4194304
  const size_t pStr = (size_t)kM * kD;

  // --- weight prep ---
  cast_transpose_kernel<<<dim3(kD / 32, kD / 32), dim3(32, 32), 0, stream>>>(
      Wo, WoT, kD, kD, (float)kS);                 // WoT[n][f] = 2048*Wo[f][n]
  cast_bf16_kernel<<<dim3(kD * kD / 1024), dim3(256), 0, stream>>>(Wv, WvBf, kD * kD);
  bias_gemv_part_kernel<<<dim3(128), dim3(256), 0, stream>>>(bv, Wo, bprt);
  bias_gemv_fin_kernel<<<dim3(4), dim3(256), 0, stream>>>(bprt, bo, bc);
  cast_bf16_kernel<<<dim3(nZ / 1024), dim3(256), 0, stream>>>(z, zbf, nZ);

  // WcT = (2048*Wv@Wo)^T via 128-tile split-K x4, then combine + I + bf16
  gemm_bt<0, 0><<<dim3(256), dim3(256), 0, stream>>>(
      WoT, WvBf, nullptr, wcp, kD, kD, kD, kD / 128, 64, 256, (size_t)kD * kD);
  combine_wc_kernel<<<dim3(1024), dim3(256), 0, stream>>>(wcp, WcT);

  // att partials = z @ (I+Wc) + bc, 256-tile 8-phase, split-K x4 (grid 256)
  gemm256<0, 0><<<dim3(256), dim3(512), 0, stream>>>(
      zbf, WcT, bc, attP, kM, kD, kD, kD / 256, 64, 256, pStr);

  // h1 = LN(sum of 4 partials) -> bf16
  ln4_bf16_kernel<<<dim3(kM), dim3(256), 0, stream>>>(attP, pStr, lng, lnb, h1bf);

  // FF1: a1 = relu(h1 @ W1 + b1), 256-tile 8-phase, grid 256, no split
  cast_transpose_kernel<<<dim3(kFF / 32, kD / 32), dim3(32, 32), 0, stream>>>(
      W1, wT, kD, kFF, 1.0f);
  gemm256<1, 1><<<dim3(256), dim3(512), 0, stream>>>(
      h1bf, wT, b1, a1, kM, kFF, kD, kFF / 256, 256, kD, 0);

  // FF2: ffP = a1 @ W2 + b2, 256-tile 8-phase, split-K x4 (grid 256)
  cast_transpose_kernel<<<dim3(kD / 32, kFF / 32), dim3(32, 32), 0, stream>>>(
      W2, wT, kFF, kD, 1.0f);
  gemm256<0, 0><<<dim3(256), dim3(512), 0, stream>>>(
      a1, wT, b2, ffP, kM, kD, kFF, kD / 256, 64, kFF / 4, pStr);

  // out = LN(h1 + sum of 4 ff partials)
  ln_fin_kernel<<<dim3(kM), dim3(256), 0, stream>>>(h1bf, ffP, pStr, lng, lnb, out);
}

// Round 6
// 189.414 us; speedup vs baseline: 1.0401x; 1.0401x over previous
//
#include <hip/hip_runtime.h>

// Problem constants (from reference)
static constexpr int kB = 2, kS = 2048, kD = 1024, kFF = 4096;
static constexpr int kM = kB * kS;  // 4096 token rows
static constexpr size_t MB = 1u << 20;

typedef __attribute__((ext_vector_type(8))) short short8;
typedef __attribute__((ext_vector_type(4))) float f32x4;

__device__ __forceinline__ unsigned short f2bf(float f) {
  union { float f; unsigned int u; } c; c.f = f;
  unsigned int u = c.u;
  unsigned int r = u + 0x7FFFu + ((u >> 16) & 1u);  // RNE
  return (unsigned short)(r >> 16);
}

__device__ __forceinline__ float bf2f(unsigned short b) {
  union { unsigned int u; float f; } c;
  c.u = ((unsigned int)b) << 16;
  return c.f;
}

__device__ __forceinline__ void gload_lds16(const void* g, void* l) {
  __builtin_amdgcn_global_load_lds(
      (const __attribute__((address_space(1))) void*)g,
      (__attribute__((address_space(3))) void*)l, 16, 0, 0);
}

// ---------------- cast fp32 -> bf16 (vectorized) ----------------
__global__ __launch_bounds__(256) void cast_bf16_kernel(
    const float* __restrict__ in, unsigned short* __restrict__ out, int n) {
  int i = (blockIdx.x * 256 + threadIdx.x) * 4;
  if (i >= n) return;
  float4 v = *(const float4*)(in + i);
  ushort4 o;
  o.x = f2bf(v.x); o.y = f2bf(v.y); o.z = f2bf(v.z); o.w = f2bf(v.w);
  *(ushort4*)(out + i) = o;
}

// ------------- cast + transpose: W[K][N] fp32 -> Wt[N][K] bf16 (× scale) -------------
__global__ __launch_bounds__(1024) void cast_transpose_kernel(
    const float* __restrict__ W, unsigned short* __restrict__ Wt,
    int K, int N, float scale) {
  __shared__ float tile[32][33];
  int nb = blockIdx.x * 32, kb = blockIdx.y * 32;
  int tx = threadIdx.x, ty = threadIdx.y;
  tile[ty][tx] = W[(size_t)(kb + ty) * N + (nb + tx)];
  __syncthreads();
  Wt[(size_t)(nb + ty) * K + (kb + tx)] = f2bf(tile[tx][ty] * scale);
}

// --------- parallel GEMV phase 1: partial[b][n] = sum_{f in block b} bv[f]*Wo[f][n] ---
__global__ __launch_bounds__(256) void bias_gemv_part_kernel(
    const float* __restrict__ bv, const float* __restrict__ Wo,
    float* __restrict__ partial) {
  const int b = blockIdx.x, t = threadIdx.x;
  const int c = t * 4;
  float4 acc = {0.f, 0.f, 0.f, 0.f};
#pragma unroll
  for (int r = 0; r < 8; ++r) {
    const int f = b * 8 + r;
    const float s = bv[f];
    float4 w = *(const float4*)(Wo + (size_t)f * 1024 + c);
    acc.x = fmaf(s, w.x, acc.x);
    acc.y = fmaf(s, w.y, acc.y);
    acc.z = fmaf(s, w.z, acc.z);
    acc.w = fmaf(s, w.w, acc.w);
  }
  *(float4*)(partial + (size_t)b * 1024 + c) = acc;
}

// --------- GEMV phase 2: bc[n] = 2048 * sum_b partial[b][n] + bo[n] ---------
__global__ __launch_bounds__(256) void bias_gemv_fin_kernel(
    const float* __restrict__ partial, const float* __restrict__ bo,
    float* __restrict__ bc) {
  const int n = blockIdx.x * 256 + threadIdx.x;
  float acc = 0.0f;
#pragma unroll 8
  for (int b = 0; b < 128; ++b) acc += partial[(size_t)b * 1024 + n];
  bc[n] = 2048.0f * acc + bo[n];
}

// -------- combine 4 fp32 split-K partials of Wc, add identity, cast bf16 --------
__global__ __launch_bounds__(256) void combine_wc_kernel(
    const float* __restrict__ P, unsigned short* __restrict__ Wt) {
  const int i = (blockIdx.x * 256 + threadIdx.x) * 4;  // grid 1024
  const int MN = 1024 * 1024;
  float4 s0 = *(const float4*)(P + i);
  float4 s1 = *(const float4*)(P + MN + i);
  float4 s2 = *(const float4*)(P + 2 * MN + i);
  float4 s3 = *(const float4*)(P + 3 * MN + i);
  const int row = i >> 10, col = i & 1023;
  float v0 = s0.x + s1.x + s2.x + s3.x + (row == col + 0 ? 1.0f : 0.0f);
  float v1 = s0.y + s1.y + s2.y + s3.y + (row == col + 1 ? 1.0f : 0.0f);
  float v2 = s0.z + s1.z + s2.z + s3.z + (row == col + 2 ? 1.0f : 0.0f);
  float v3 = s0.w + s1.w + s2.w + s3.w + (row == col + 3 ? 1.0f : 0.0f);
  ushort4 o; o.x = f2bf(v0); o.y = f2bf(v1); o.z = f2bf(v2); o.w = f2bf(v3);
  *(ushort4*)(Wt + i) = o;
}

// ---------------- 128x128 2-phase GEMM (kept for the small Wc product) ----------------
template <int OUT_BF16, int RELU>
__global__ __launch_bounds__(256) void gemm_bt(
    const unsigned short* __restrict__ A, const unsigned short* __restrict__ Bt,
    const float* __restrict__ bias, void* __restrict__ Cout,
    int M, int N, int K, int nXtiles, int nTilesPerSplit, int kSplitLen,
    size_t cSplitStride) {
  __shared__ __align__(16) unsigned short sA[128 * 64];
  __shared__ __align__(16) unsigned short sB[128 * 64];
  const int tid = threadIdx.x;
  const int wave = tid >> 6, lane = tid & 63;
  const int wr = wave >> 1, wc = wave & 1;
  const int nwg = gridDim.x;
  const int q = nwg >> 3, r = nwg & 7;
  const int xcd = blockIdx.x & 7, pos = blockIdx.x >> 3;
  const int swz = (xcd < r) ? (xcd * (q + 1) + pos) : (r * (q + 1) + (xcd - r) * q + pos);
  const int split = swz / nTilesPerSplit, rem = swz % nTilesPerSplit;
  const int m0 = (rem / nXtiles) * 128, n0 = (rem % nXtiles) * 128;
  const int kBeg = split * kSplitLen, kEnd = kBeg + kSplitLen;
  const int srow = lane >> 3;
  const int scol = ((lane & 7) ^ srow) * 8;

  f32x4 acc[4][4] = {};

  for (int k0 = kBeg; k0 < kEnd; k0 += 64) {
#pragma unroll
    for (int i = 0; i < 4; ++i) {
      const int chunk = i * 4 + wave;
      const int rr = chunk * 8 + srow;
      gload_lds16(A + (size_t)(m0 + rr) * K + (k0 + scol), &sA[chunk * 512]);
      gload_lds16(Bt + (size_t)(n0 + rr) * K + (k0 + scol), &sB[chunk * 512]);
    }
    __syncthreads();
#pragma unroll
    for (int kk = 0; kk < 64; kk += 32) {
      const int kcol = kk + (lane >> 4) * 8;
      const int kswz = (lane & 7) * 8;
      short8 af[4], bfr[4];
#pragma unroll
      for (int m = 0; m < 4; ++m)
        af[m] = *(const short8*)&sA[(wr * 64 + m * 16 + (lane & 15)) * 64 + (kcol ^ kswz)];
#pragma unroll
      for (int n = 0; n < 4; ++n)
        bfr[n] = *(const short8*)&sB[(wc * 64 + n * 16 + (lane & 15)) * 64 + (kcol ^ kswz)];
#pragma unroll
      for (int m = 0; m < 4; ++m)
#pragma unroll
        for (int n = 0; n < 4; ++n)
          acc[m][n] = __builtin_amdgcn_mfma_f32_16x16x32_bf16(af[m], bfr[n], acc[m][n], 0, 0, 0);
    }
    __syncthreads();
  }

  const int cl = lane & 15, rg = lane >> 4;
  const float* bptr = (split == 0) ? bias : nullptr;
#pragma unroll
  for (int n = 0; n < 4; ++n) {
    const int col = n0 + wc * 64 + n * 16 + cl;
    const float bias_v = bptr ? bptr[col] : 0.0f;
#pragma unroll
    for (int m = 0; m < 4; ++m) {
      const int rbase = m0 + wr * 64 + m * 16 + rg * 4;
#pragma unroll
      for (int j = 0; j < 4; ++j) {
        float v = acc[m][n][j] + bias_v;
        if (RELU) v = fmaxf(v, 0.0f);
        if (OUT_BF16)
          ((unsigned short*)Cout)[(size_t)(rbase + j) * N + col] = f2bf(v);
        else
          ((float*)Cout)[split * cSplitStride + (size_t)(rbase + j) * N + col] = v;
      }
    }
  }
}

// ================= 256x256 8-phase GEMM, counted-vmcnt pipeline =================
// 8 waves (2M x 4N), BK=64, double-buffered A/B (4 x 32KB LDS).
// Stage units per K-tile (per wave, 2 gload_lds each):
//   U0 = A quarters {0,2} (A-half for mh=0)    U2 = A quarters {1,3} (mh=1)
//   U1 = B comb0 (rows wq*64+[0,32))           U3 = B comb1 (rows wq*64+32+[0,32))
// Tile t issues U0,U1(t+1) at phase0 and U2,U3(t+1) at phase1.
// Waits: vmcnt(4) at phase0 (retires U2,U3 of current tile) and phase3
// (retires U0,U1 of next tile). Queue NEVER drains to 0 in steady state (T4).
// Phase order Q(0,0),Q(0,1),Q(1,1),Q(1,0) with register fragment reuse:
// ds_read_b128 per phase = 12/4/8/0 (24/tile, each fragment read once).

#define BARRIER asm volatile("s_barrier" ::: "memory")

#define ST_A(DST, G, KOFS) \
  gload_lds16(aSrc + (size_t)(G) * 64 * K + (KOFS), &DST[(G) * 4096 + aLds]);

#define ST_B(DST, C, J, KOFS) \
  gload_lds16(bSrc + (size_t)((J) * 128 + (C) * 32) * K + (KOFS), \
              &DST[((J) * 128 + (C) * 32) * 64 + bLds]);

#define RD_A(DST, SRC, MH) do { \
  _Pragma("unroll") \
  for (int fm = 0; fm < 4; ++fm) { \
    const int ra = (wr * 128 + (MH) * 64 + fm * 16 + l15) * 64; \
    DST[fm][0] = *(const short8*)&SRC[ra + cK0]; \
    DST[fm][1] = *(const short8*)&SRC[ra + cK1]; \
  } } while (0)

#define RD_B(DST, SRC, NH) do { \
  _Pragma("unroll") \
  for (int fn = 0; fn < 2; ++fn) { \
    const int rb = (wq * 64 + (NH) * 32 + fn * 16 + l15) * 64; \
    DST[fn][0] = *(const short8*)&SRC[rb + cK0]; \
    DST[fn][1] = *(const short8*)&SRC[rb + cK1]; \
  } } while (0)

#define MFMA_Q(AH, BH, MH, NH) do { \
  __builtin_amdgcn_s_setprio(1); \
  _Pragma("unroll") \
  for (int fm = 0; fm < 4; ++fm) { \
    _Pragma("unroll") \
    for (int fn = 0; fn < 2; ++fn) { \
      acc[(MH) * 4 + fm][(NH) * 2 + fn] = __builtin_amdgcn_mfma_f32_16x16x32_bf16( \
          AH[fm][0], BH[fn][0], acc[(MH) * 4 + fm][(NH) * 2 + fn], 0, 0, 0); \
      acc[(MH) * 4 + fm][(NH) * 2 + fn] = __builtin_amdgcn_mfma_f32_16x16x32_bf16( \
          AH[fm][1], BH[fn][1], acc[(MH) * 4 + fm][(NH) * 2 + fn], 0, 0, 0); \
    } \
  } \
  __builtin_amdgcn_s_setprio(0); \
  } while (0)

#define KTILE(SAR, SBR, SAW, SBW, MORE, KNEXT)                          \
  {                                                                     \
    short8 a0[4][2], a1[4][2], b0[2][2], b1[2][2];                      \
    /* phase 0: Q(0,0) */                                               \
    RD_A(a0, SAR, 0); RD_B(b0, SBR, 0);                                 \
    if (MORE) {                                                         \
      ST_A(SAW, 0, KNEXT) ST_A(SAW, 2, KNEXT)                           \
      ST_B(SBW, 0, 0, KNEXT) ST_B(SBW, 0, 1, KNEXT)                     \
      asm volatile("s_waitcnt vmcnt(4)" ::: "memory");                  \
    } else {                                                            \
      asm volatile("s_waitcnt vmcnt(0)" ::: "memory");                  \
    }                                                                   \
    BARRIER;                                                            \
    MFMA_Q(a0, b0, 0, 0);                                               \
    BARRIER;                                                            \
    /* phase 1: Q(0,1) */                                               \
    RD_B(b1, SBR, 1);                                                   \
    if (MORE) {                                                         \
      ST_A(SAW, 1, KNEXT) ST_A(SAW, 3, KNEXT)                           \
      ST_B(SBW, 1, 0, KNEXT) ST_B(SBW, 1, 1, KNEXT)                     \
    }                                                                   \
    BARRIER;                                                            \
    MFMA_Q(a0, b1, 0, 1);                                               \
    BARRIER;                                                            \
    /* phase 2: Q(1,1) */                                               \
    RD_A(a1, SAR, 1);                                                   \
    BARRIER;                                                            \
    MFMA_Q(a1, b1, 1, 1);                                               \
    BARRIER;                                                            \
    /* phase 3: Q(1,0) */                                               \
    if (MORE) asm volatile("s_waitcnt vmcnt(4)" ::: "memory");          \
    BARRIER;                                                            \
    MFMA_Q(a1, b0, 1, 0);                                               \
    BARRIER;                                                            \
  }

template <int OUT_BF16, int RELU>
__global__ __launch_bounds__(512, 2) void gemm256(
    const unsigned short* __restrict__ A, const unsigned short* __restrict__ Bt,
    const float* __restrict__ bias, void* __restrict__ Cout,
    int M, int N, int K, int nXtiles, int nTilesPerSplit, int kSplitLen,
    size_t cStride) {
  __shared__ __align__(16) unsigned short sA0[256 * 64];
  __shared__ __align__(16) unsigned short sA1[256 * 64];
  __shared__ __align__(16) unsigned short sB0[256 * 64];
  __shared__ __align__(16) unsigned short sB1[256 * 64];

  const int tid = threadIdx.x;
  const int wid = tid >> 6, lane = tid & 63;
  const int wr = wid >> 2, wq = wid & 3;
  const int l15 = lane & 15, l7 = lane & 7, l4 = lane >> 4;

  // T1: bijective XCD swizzle
  const int nwg = gridDim.x;
  const int q = nwg >> 3, r = nwg & 7;
  const int xcd = blockIdx.x & 7, pos = blockIdx.x >> 3;
  const int swz = (xcd < r) ? (xcd * (q + 1) + pos) : (r * (q + 1) + (xcd - r) * q + pos);
  const int split = swz / nTilesPerSplit, rem = swz % nTilesPerSplit;
  const int m0 = (rem / nXtiles) * 256, n0 = (rem % nXtiles) * 256;
  const int kBeg = split * kSplitLen;
  const int nt = kSplitLen >> 6;  // K-tiles (even: 4 or 16 here)

  // staging addressing. Source is per-lane (row = base + lane>>3, col slot
  // pre-swizzled by row&7); LDS dest is wave-uniform, HW adds lane*16B.
  const int srow = lane >> 3;
  const int sColOff = ((l7 ^ srow) << 3);
  const unsigned short* aSrc = A + (size_t)(m0 + wid * 8 + srow) * K + kBeg + sColOff;
  const int bRow = (wid >> 2) * 64 + (wid & 3) * 8;
  const unsigned short* bSrc = Bt + (size_t)(n0 + bRow + srow) * K + kBeg + sColOff;
  const int aLds = wid * 512;   // element offset (wave's 8-row block in each 64-row grp)
  const int bLds = bRow * 64;   // element offset base for B comb loads

  // read-side swizzled K offsets (elements): slot = (ks*4 + l4) ^ (row&7 == l7)
  const int cK0 = ((l4 ^ l7) << 3);
  const int cK1 = (((4 + l4) ^ l7) << 3);

  f32x4 acc[8][4] = {};

  // prologue: stage tile 0 into buf0 (U0,U1 then U2,U3); wait for U0,U1.
  ST_A(sA0, 0, 0) ST_A(sA0, 2, 0) ST_B(sB0, 0, 0, 0) ST_B(sB0, 0, 1, 0)
  ST_A(sA0, 1, 0) ST_A(sA0, 3, 0) ST_B(sB0, 1, 0, 0) ST_B(sB0, 1, 1, 0)
  asm volatile("s_waitcnt vmcnt(4)" ::: "memory");
  __syncthreads();

  for (int t = 0; t < nt; t += 2) {
    KTILE(sA0, sB0, sA1, sB1, (t + 1) < nt, (t + 1) * 64)
    KTILE(sA1, sB1, sA0, sB0, (t + 2) < nt, (t + 2) * 64)
  }

  // epilogue: C-write.
  const int colBase = n0 + wq * 64;
  const int rowBase = m0 + wr * 128 + l4 * 4;
  const float* bptr = (split == 0) ? bias : nullptr;
#pragma unroll
  for (int fn = 0; fn < 4; ++fn) {
    const int col = colBase + fn * 16 + l15;
    const float bias_v = bptr ? bptr[col] : 0.0f;
#pragma unroll
    for (int fm = 0; fm < 8; ++fm) {
      const int row = rowBase + fm * 16;
#pragma unroll
      for (int j = 0; j < 4; ++j) {
        float v = acc[fm][fn][j] + bias_v;
        if (RELU) v = fmaxf(v, 0.0f);
        if (OUT_BF16)
          ((unsigned short*)Cout)[(size_t)(row + j) * N + col] = f2bf(v);
        else
          ((float*)Cout)[split * cStride + (size_t)(row + j) * N + col] = v;
      }
    }
  }
}

// -------- LN over D=1024 of sum of 4 fp32 partials -> bf16 out --------
__global__ __launch_bounds__(256) void ln4_bf16_kernel(
    const float* __restrict__ P, size_t pStr,
    const float* __restrict__ gg, const float* __restrict__ bb,
    unsigned short* __restrict__ Hb) {
  const int row = blockIdx.x, t = threadIdx.x;
  const size_t base = (size_t)row * 1024 + t * 4;
  float4 v0 = *(const float4*)(P + base);
  float4 v1 = *(const float4*)(P + pStr + base);
  float4 v2 = *(const float4*)(P + 2 * pStr + base);
  float4 v3 = *(const float4*)(P + 3 * pStr + base);
  float a0 = v0.x + v1.x + v2.x + v3.x;
  float a1 = v0.y + v1.y + v2.y + v3.y;
  float a2 = v0.z + v1.z + v2.z + v3.z;
  float a3 = v0.w + v1.w + v2.w + v3.w;
  float s = a0 + a1 + a2 + a3;
  float ss = a0 * a0 + a1 * a1 + a2 * a2 + a3 * a3;
#pragma unroll
  for (int off = 32; off > 0; off >>= 1) {
    s += __shfl_down(s, off);
    ss += __shfl_down(ss, off);
  }
  __shared__ float rs[4], rss[4];
  __shared__ float smean, srstd;
  const int wave = t >> 6, lane = t & 63;
  if (lane == 0) { rs[wave] = s; rss[wave] = ss; }
  __syncthreads();
  if (t == 0) {
    float S1 = rs[0] + rs[1] + rs[2] + rs[3];
    float S2 = rss[0] + rss[1] + rss[2] + rss[3];
    float mean = S1 * (1.0f / 1024.0f);
    float var = S2 * (1.0f / 1024.0f) - mean * mean;
    smean = mean;
    srstd = rsqrtf(var + 1e-5f);
  }
  __syncthreads();
  const float mean = smean, rstd = srstd;
  float4 gv = *(const float4*)(gg + t * 4);
  float4 bv = *(const float4*)(bb + t * 4);
  ushort4 hb;
  hb.x = f2bf((a0 - mean) * rstd * gv.x + bv.x);
  hb.y = f2bf((a1 - mean) * rstd * gv.y + bv.y);
  hb.z = f2bf((a2 - mean) * rstd * gv.z + bv.z);
  hb.w = f2bf((a3 - mean) * rstd * gv.w + bv.w);
  *(ushort4*)(Hb + base) = hb;
}

// -------- LN of (bf16 residual + sum of 4 fp32 partials) -> fp32 out --------
__global__ __launch_bounds__(256) void ln_fin_kernel(
    const unsigned short* __restrict__ Res, const float* __restrict__ P, size_t pStr,
    const float* __restrict__ gg, const float* __restrict__ bb,
    float* __restrict__ out) {
  const int row = blockIdx.x, t = threadIdx.x;
  const size_t base = (size_t)row * 1024 + t * 4;
  ushort4 rv = *(const ushort4*)(Res + base);
  float4 v0 = *(const float4*)(P + base);
  float4 v1 = *(const float4*)(P + pStr + base);
  float4 v2 = *(const float4*)(P + 2 * pStr + base);
  float4 v3 = *(const float4*)(P + 3 * pStr + base);
  float a0 = bf2f(rv.x) + v0.x + v1.x + v2.x + v3.x;
  float a1 = bf2f(rv.y) + v0.y + v1.y + v2.y + v3.y;
  float a2 = bf2f(rv.z) + v0.z + v1.z + v2.z + v3.z;
  float a3 = bf2f(rv.w) + v0.w + v1.w + v2.w + v3.w;
  float s = a0 + a1 + a2 + a3;
  float ss = a0 * a0 + a1 * a1 + a2 * a2 + a3 * a3;
#pragma unroll
  for (int off = 32; off > 0; off >>= 1) {
    s += __shfl_down(s, off);
    ss += __shfl_down(ss, off);
  }
  __shared__ float rs[4], rss[4];
  __shared__ float smean, srstd;
  const int wave = t >> 6, lane = t & 63;
  if (lane == 0) { rs[wave] = s; rss[wave] = ss; }
  __syncthreads();
  if (t == 0) {
    float S1 = rs[0] + rs[1] + rs[2] + rs[3];
    float S2 = rss[0] + rss[1] + rss[2] + rss[3];
    float mean = S1 * (1.0f / 1024.0f);
    float var = S2 * (1.0f / 1024.0f) - mean * mean;
    smean = mean;
    srstd = rsqrtf(var + 1e-5f);
  }
  __syncthreads();
  const float mean = smean, rstd = srstd;
  float4 gv = *(const float4*)(gg + t * 4);
  float4 bv = *(const float4*)(bb + t * 4);
  float4 ov;
  ov.x = (a0 - mean) * rstd * gv.x + bv.x;
  ov.y = (a1 - mean) * rstd * gv.y + bv.y;
  ov.z = (a2 - mean) * rstd * gv.z + bv.z;
  ov.w = (a3 - mean) * rstd * gv.w + bv.w;
  *(float4*)(out + base) = ov;
}

// ---------------------------------------------------------------------------
// Attention is algebraically dead: softmax over q sums to 1 per (b,h,k) column;
// summed over k -> s_bh == S == 2048 exactly. Folding the residual too:
//   h1  = LN( z @ (I + 2048*Wv@Wo) + (2048*bv@Wo + bo) )
//   out = LN( h1 + relu(h1@W1+b1)@W2 + b2 )
// ---------------------------------------------------------------------------
extern "C" void kernel_launch(void* const* d_in, const int* in_sizes, int n_in,
                              void* d_out, int out_size, void* d_ws, size_t ws_size,
                              hipStream_t stream) {
  const float* z  = (const float*)d_in[2];
  const float* Wv = (const float*)d_in[8];
  const float* bv = (const float*)d_in[9];
  const float* Wo = (const float*)d_in[10];
  const float* bo = (const float*)d_in[11];
  const float* W1 = (const float*)d_in[12];
  const float* b1 = (const float*)d_in[13];
  const float* W2 = (const float*)d_in[14];
  const float* b2 = (const float*)d_in[15];
  const float* lng = (const float*)d_in[16];
  const float* lnb = (const float*)d_in[17];
  float* out = (float*)d_out;

  char* ws = (char*)d_ws;
  float*          attP = (float*)(ws + 0 * MB);
  float*          ffP  = (float*)(ws + 0 * MB);
  unsigned short* zbf  = (unsigned short*)(ws + 64 * MB);
  unsigned short* a1   = (unsigned short*)(ws + 64 * MB);
  unsigned short* WoT  = (unsigned short*)(ws + 72 * MB);
  unsigned short* WvBf = (unsigned short*)(ws + 74 * MB);
  unsigned short* WcT  = (unsigned short*)(ws + 76 * MB);
  float*          bc   = (float*)(ws + 78 * MB);
  float*          bprt = (float*)(ws + 78 * MB + 65536);
  float*          wcp  = (float*)(ws + 80 * MB);
  unsigned short* wT   = (unsigned short*)(ws + 96 * MB);
  unsigned short* h1bf = (unsigned short*)(ws + 104 * MB);

  const int nZ = kM * kD;  // 4194304
  const size_t pStr = (size_t)kM * kD;

  // --- weight prep ---
  cast_transpose_kernel<<<dim3(kD / 32, kD / 32), dim3(32, 32), 0, stream>>>(
      Wo, WoT, kD, kD, (float)kS);                 // WoT[n][f] = 2048*Wo[f][n]
  cast_bf16_kernel<<<dim3(kD * kD / 1024), dim3(256), 0, stream>>>(Wv, WvBf, kD * kD);
  bias_gemv_part_kernel<<<dim3(128), dim3(256), 0, stream>>>(bv, Wo, bprt);
  bias_gemv_fin_kernel<<<dim3(4), dim3(256), 0, stream>>>(bprt, bo, bc);
  cast_bf16_kernel<<<dim3(nZ / 1024), dim3(256), 0, stream>>>(z, zbf, nZ);

  // WcT = (2048*Wv@Wo)^T via 128-tile split-K x4, then combine + I + bf16
  gemm_bt<0, 0><<<dim3(256), dim3(256), 0, stream>>>(
      WoT, WvBf, nullptr, wcp, kD, kD, kD, kD / 128, 64, 256, (size_t)kD * kD);
  combine_wc_kernel<<<dim3(1024), dim3(256), 0, stream>>>(wcp, WcT);

  // att partials = z @ (I+Wc) + bc, 256-tile pipelined, split-K x4 (grid 256)
  gemm256<0, 0><<<dim3(256), dim3(512), 0, stream>>>(
      zbf, WcT, bc, attP, kM, kD, kD, kD / 256, 64, 256, pStr);

  // h1 = LN(sum of 4 partials) -> bf16
  ln4_bf16_kernel<<<dim3(kM), dim3(256), 0, stream>>>(attP, pStr, lng, lnb, h1bf);

  // FF1: a1 = relu(h1 @ W1 + b1), grid 256, no split
  cast_transpose_kernel<<<dim3(kFF / 32, kD / 32), dim3(32, 32), 0, stream>>>(
      W1, wT, kD, kFF, 1.0f);
  gemm256<1, 1><<<dim3(256), dim3(512), 0, stream>>>(
      h1bf, wT, b1, a1, kM, kFF, kD, kFF / 256, 256, kD, 0);

  // FF2: ffP = a1 @ W2 + b2, split-K x4 (grid 256)
  cast_transpose_kernel<<<dim3(kD / 32, kFF / 32), dim3(32, 32), 0, stream>>>(
      W2, wT, kFF, kD, 1.0f);
  gemm256<0, 0><<<dim3(256), dim3(512), 0, stream>>>(
      a1, wT, b2, ffP, kM, kD, kFF, kD / 256, 64, kFF / 4, pStr);

  // out = LN(h1 + sum of 4 ff partials)
  ln_fin_kernel<<<dim3(kM), dim3(256), 0, stream>>>(h1bf, ffP, pStr, lng, lnb, out);
}